// Round 7
// baseline (1174.378 us; speedup 1.0000x reference)
//
#include <hip/hip_runtime.h>
#include <math.h>

#define NODES 30000
#define NEDGE 480000
#define ETOT  (NODES + NEDGE)
#define NGRAPH 30
#define DIN 256
#define DH 64
#define CAP 128

typedef __bf16 bf16x8 __attribute__((ext_vector_type(8)));
typedef float  f32x4  __attribute__((ext_vector_type(4)));

static __device__ __forceinline__ float elu_f(float x){ return x > 0.f ? x : expm1f(x); }
static __device__ __forceinline__ float bf_lo(unsigned v){ return __uint_as_float(v << 16); }
static __device__ __forceinline__ float bf_hi(unsigned v){ return __uint_as_float(v & 0xffff0000u); }
static __device__ __forceinline__ unsigned pack_bf2(float a, float b){
  __bf16 ob[2] = {(__bf16)a, (__bf16)b};
  return *(unsigned*)ob;
}

// ---------------- CSR: count + scan fused (last-block pattern) ----------------
__global__ __launch_bounds__(256) void k_countscan(const int* __restrict__ ei,
    int* __restrict__ deg, int* __restrict__ rowptr, int* __restrict__ done){
  int t = threadIdx.x;
  int e = blockIdx.x*256 + t;
  if (e < ETOT){
    int dst = (e < NEDGE) ? ei[NEDGE + e] : (e - NEDGE);
    atomicAdd(&deg[dst], 1);
  }
  __threadfence();
  __shared__ int lastf;
  if (t == 0) lastf = (atomicAdd(done, 1) == (int)gridDim.x - 1);
  __syncthreads();
  if (!lastf) return;
  __threadfence();
  __shared__ int s[256];
  const int CH = (NODES + 255)/256;
  int base = t*CH;
  int local = 0;
  for (int i = 0; i < CH; i++){ int idx = base + i; if (idx < NODES) local += deg[idx]; }
  s[t] = local; __syncthreads();
  for (int off = 1; off < 256; off <<= 1){
    int v = (t >= off) ? s[t - off] : 0;
    __syncthreads();
    s[t] += v;
    __syncthreads();
  }
  int run = s[t] - local;
  for (int i = 0; i < CH; i++){
    int idx = base + i;
    if (idx < NODES){ rowptr[idx] = run; run += deg[idx]; }
  }
  if (t == 255) rowptr[NODES] = s[255];
}

__global__ void k_fill(const int* __restrict__ ei, const int* __restrict__ rowptr,
                       int* __restrict__ cursor, int* __restrict__ colA){
  int e = blockIdx.x*256 + threadIdx.x;
  if (e >= ETOT) return;
  int src, dst;
  if (e < NEDGE){ src = ei[e]; dst = ei[NEDGE + e]; }
  else          { src = e - NEDGE; dst = src; }
  int pos = atomicAdd(&cursor[dst], 1);
  colA[rowptr[dst] + pos] = src;
}

// ---------------- fused input cast + all weight transposes ----------------
#define NCAST4 (NODES*DIN/4)
#define TW0 (512*256)
#define TW1 (512*512)
#define TW2 (64*512)
__global__ void k_prep(const float* __restrict__ x, __bf16* __restrict__ xb0,
                       const float* __restrict__ W0, const float* __restrict__ W1,
                       const float* __restrict__ W2, __bf16* __restrict__ Wt0,
                       __bf16* __restrict__ Wt1, __bf16* __restrict__ Wt2){
  int idx = blockIdx.x*256 + threadIdx.x;
  if (idx < NCAST4){
    float4 v = ((const float4*)x)[idx];
    __bf16 o[4] = {(__bf16)v.x, (__bf16)v.y, (__bf16)v.z, (__bf16)v.w};
    *(uint2*)(xb0 + (size_t)idx*4) = *(const uint2*)o;
    return;
  }
  int j = idx - NCAST4;
  if (j < TW0){
    int n = j >> 8, k = j & 255;
    Wt0[j] = (__bf16)W0[(size_t)k*512 + n];
  } else if (j < TW0 + TW1){
    int j1 = j - TW0;
    int n = j1 >> 9, k = j1 & 511;
    Wt1[j1] = (__bf16)W1[(size_t)k*512 + n];
  } else if (j < TW0 + TW1 + TW2){
    int j2 = j - TW0 - TW1;
    int n = j2 >> 9, k = j2 & 511;
    Wt2[j2] = (__bf16)W2[(size_t)k*64 + n];
  }
}

// ---------------- bf16 MFMA GEMM + fused attention scores ----------------
#define LSTR 72
__global__ __launch_bounds__(256) void k_gemm_bf16(const __bf16* __restrict__ A,
    const __bf16* __restrict__ Bt, __bf16* __restrict__ C,
    const float* __restrict__ asrc, const float* __restrict__ adst,
    float* __restrict__ ssrc, float* __restrict__ sdst, int heads,
    int M, int N, int K){
  __shared__ __align__(16) __bf16 As[128*LSTR];
  __shared__ __align__(16) __bf16 Bs[128*LSTR];
  int tid  = threadIdx.x;
  int lane = tid & 63, wave = tid >> 6;
  int wr = wave >> 1, wc = wave & 1;
  int q = lane >> 4, r = lane & 15;
  int rowBase = blockIdx.y * 128, colBase = blockIdx.x * 128;
  f32x4 acc[4][4] = {};
  for (int k0 = 0; k0 < K; k0 += 64){
    #pragma unroll
    for (int p = 0; p < 4; p++){
      int lin = p*256 + tid;
      int rr = lin >> 3, ko = (lin & 7) * 8;
      uint4 va = make_uint4(0,0,0,0);
      int gr = rowBase + rr;
      if (gr < M) va = *(const uint4*)(A + (size_t)gr*K + k0 + ko);
      *(uint4*)(&As[rr*LSTR + ko]) = va;
      uint4 vb = make_uint4(0,0,0,0);
      int gn = colBase + rr;
      if (gn < N) vb = *(const uint4*)(Bt + (size_t)gn*K + k0 + ko);
      *(uint4*)(&Bs[rr*LSTR + ko]) = vb;
    }
    __syncthreads();
    #pragma unroll
    for (int kk = 0; kk < 2; kk++){
      bf16x8 af[4], bfr[4];
      #pragma unroll
      for (int i = 0; i < 4; i++) af[i]  = *(const bf16x8*)(&As[(wr*64 + i*16 + r)*LSTR + kk*32 + q*8]);
      #pragma unroll
      for (int j = 0; j < 4; j++) bfr[j] = *(const bf16x8*)(&Bs[(wc*64 + j*16 + r)*LSTR + kk*32 + q*8]);
      #pragma unroll
      for (int i = 0; i < 4; i++)
        #pragma unroll
        for (int j = 0; j < 4; j++)
          acc[i][j] = __builtin_amdgcn_mfma_f32_16x16x32_bf16(af[i], bfr[j], acc[i][j], 0, 0, 0);
    }
    __syncthreads();
  }
  #pragma unroll
  for (int i = 0; i < 4; i++){
    #pragma unroll
    for (int j = 0; j < 4; j++){
      int col = colBase + wc*64 + j*16 + r;
      if (col >= N) continue;
      #pragma unroll
      for (int v = 0; v < 4; v++){
        int row = rowBase + wr*64 + i*16 + q*4 + v;
        if (row < M) C[(size_t)row*N + col] = (__bf16)acc[i][j][v];
      }
    }
  }
  // fused attention scores: head hb owns cols [hb*64, hb*64+64)
  int colW = colBase + wc*64;
  if (colW < N){
    int hb = colW >> 6;
    float a_s[4], a_d[4];
    #pragma unroll
    for (int j = 0; j < 4; j++){
      a_s[j] = asrc[hb*64 + j*16 + r];
      a_d[j] = adst[hb*64 + j*16 + r];
    }
    #pragma unroll
    for (int i = 0; i < 4; i++){
      #pragma unroll
      for (int v = 0; v < 4; v++){
        float s1 = 0.f, s2 = 0.f;
        #pragma unroll
        for (int j = 0; j < 4; j++){
          float av = acc[i][j][v];
          s1 += av * a_s[j];
          s2 += av * a_d[j];
        }
        #pragma unroll
        for (int off = 1; off < 16; off <<= 1){
          s1 += __shfl_xor(s1, off, 64);
          s2 += __shfl_xor(s2, off, 64);
        }
        if (r == 0){
          int row = rowBase + wr*64 + i*16 + q*4 + v;
          if (row < M){
            ssrc[(size_t)row*heads + hb] = s1;
            sdst[(size_t)row*heads + hb] = s2;
          }
        }
      }
    }
  }
}

// ---------------- GAT aggregation, 8 heads; 4 feats/thread, 2 edges/round ----------------
__global__ __launch_bounds__(256) void k_gatagg8(const __bf16* __restrict__ hb,
    const float* __restrict__ ssrc, const float* __restrict__ sdst,
    const int* __restrict__ rowptr, const int* __restrict__ colA,
    const float* __restrict__ bias, __bf16* __restrict__ outb){
  int n = blockIdx.x;
  int t = threadIdx.x;
  __shared__ int ecol[CAP];
  __shared__ float p[CAP][9];
  __shared__ float racc[512];
  __shared__ float dhv[8], sdsh[8], mh[8];
  int base = rowptr[n];
  int deg = rowptr[n+1] - base;
  if (t < 8) sdsh[t] = sdst[(size_t)n*8 + t];
  __syncthreads();
  int g = t >> 5, l = t & 31;
  int half = t >> 7;          // 0 or 1: which edge parity this thread gathers
  int tf = t & 127;           // feature-quad index (4 feats each -> 512)
  int f4 = tf * 4;
  int hh4 = tf >> 4;          // head of this feature quad
  if (deg <= CAP){
    if (t < deg){
      int c = colA[base + t];
      ecol[t] = c;
      const float4* sp = (const float4*)(ssrc + (size_t)c*8);
      float4 s0 = sp[0], s1 = sp[1];
      float v;
      v = s0.x + sdsh[0]; p[t][0] = v > 0.f ? v : 0.2f*v;
      v = s0.y + sdsh[1]; p[t][1] = v > 0.f ? v : 0.2f*v;
      v = s0.z + sdsh[2]; p[t][2] = v > 0.f ? v : 0.2f*v;
      v = s0.w + sdsh[3]; p[t][3] = v > 0.f ? v : 0.2f*v;
      v = s1.x + sdsh[4]; p[t][4] = v > 0.f ? v : 0.2f*v;
      v = s1.y + sdsh[5]; p[t][5] = v > 0.f ? v : 0.2f*v;
      v = s1.z + sdsh[6]; p[t][6] = v > 0.f ? v : 0.2f*v;
      v = s1.w + sdsh[7]; p[t][7] = v > 0.f ? v : 0.2f*v;
    }
    __syncthreads();
    // softmax per head: group g = head, 32 lanes over edges
    {
      float m = -1e30f;
      for (int e = l; e < deg; e += 32) m = fmaxf(m, p[e][g]);
      #pragma unroll
      for (int off = 1; off < 32; off <<= 1) m = fmaxf(m, __shfl_xor(m, off, 64));
      float d = 0.f;
      for (int e = l; e < deg; e += 32){ float xv = __expf(p[e][g] - m); p[e][g] = xv; d += xv; }
      #pragma unroll
      for (int off = 1; off < 32; off <<= 1) d += __shfl_xor(d, off, 64);
      if (l == 0) dhv[g] = 1.f / (d + 1e-16f);
    }
    __syncthreads();
    // gather: 128 threads cover a full 1KB row; two halves take alternating edges
    float4 a = make_float4(0.f, 0.f, 0.f, 0.f);
    int e = half;
    for (; e + 2 < deg; e += 4){
      int c0 = ecol[e], c1 = ecol[e+2];
      float p0 = p[e][hh4], p1 = p[e+2][hh4];
      uint2 v0 = *(const uint2*)(hb + (size_t)c0*512 + f4);
      uint2 v1 = *(const uint2*)(hb + (size_t)c1*512 + f4);
      a.x += p0*bf_lo(v0.x); a.y += p0*bf_hi(v0.x);
      a.z += p0*bf_lo(v0.y); a.w += p0*bf_hi(v0.y);
      a.x += p1*bf_lo(v1.x); a.y += p1*bf_hi(v1.x);
      a.z += p1*bf_lo(v1.y); a.w += p1*bf_hi(v1.y);
    }
    for (; e < deg; e += 2){
      int c = ecol[e];
      float pe = p[e][hh4];
      uint2 v = *(const uint2*)(hb + (size_t)c*512 + f4);
      a.x += pe*bf_lo(v.x); a.y += pe*bf_hi(v.x);
      a.z += pe*bf_lo(v.y); a.w += pe*bf_hi(v.y);
    }
    if (half == 1) *(float4*)&racc[f4] = a;
    __syncthreads();
    if (half == 0){
      float4 o = *(const float4*)&racc[f4];
      float rcp = dhv[hh4];
      float4 bb = *(const float4*)(bias + f4);
      float r0 = (a.x + o.x)*rcp + bb.x;
      float r1 = (a.y + o.y)*rcp + bb.y;
      float r2 = (a.z + o.z)*rcp + bb.z;
      float r3 = (a.w + o.w)*rcp + bb.w;
      uint2 st; st.x = pack_bf2(r0, r1); st.y = pack_bf2(r2, r3);
      *(uint2*)(outb + (size_t)n*512 + f4) = st;
    }
  } else {
    // slow path (deg > CAP; statistically never hit)
    float m = -1e30f;
    for (int e = l; e < deg; e += 32){
      int c = colA[base + e];
      float sc = ssrc[(size_t)c*8 + g] + sdsh[g];
      sc = sc > 0.f ? sc : 0.2f*sc;
      m = fmaxf(m, sc);
    }
    #pragma unroll
    for (int off = 1; off < 32; off <<= 1) m = fmaxf(m, __shfl_xor(m, off, 64));
    if (l == 0) mh[g] = m;
    __syncthreads();
    float d = 0.f;
    float mm = mh[g];
    for (int e = l; e < deg; e += 32){
      int c = colA[base + e];
      float sc = ssrc[(size_t)c*8 + g] + sdsh[g];
      sc = sc > 0.f ? sc : 0.2f*sc;
      d += __expf(sc - mm);
    }
    #pragma unroll
    for (int off = 1; off < 32; off <<= 1) d += __shfl_xor(d, off, 64);
    if (l == 0) dhv[g] = 1.f / (d + 1e-16f);
    __syncthreads();
    float4 a = make_float4(0.f, 0.f, 0.f, 0.f);
    float mhh = mh[hh4];
    float sdd = sdsh[hh4];
    for (int e = half; e < deg; e += 2){
      int c = colA[base + e];
      float sc = ssrc[(size_t)c*8 + hh4] + sdd;
      sc = sc > 0.f ? sc : 0.2f*sc;
      float pe = __expf(sc - mhh);
      uint2 v = *(const uint2*)(hb + (size_t)c*512 + f4);
      a.x += pe*bf_lo(v.x); a.y += pe*bf_hi(v.x);
      a.z += pe*bf_lo(v.y); a.w += pe*bf_hi(v.y);
    }
    if (half == 1) *(float4*)&racc[f4] = a;
    __syncthreads();
    if (half == 0){
      float4 o = *(const float4*)&racc[f4];
      float rcp = dhv[hh4];
      float4 bb = *(const float4*)(bias + f4);
      float r0 = (a.x + o.x)*rcp + bb.x;
      float r1 = (a.y + o.y)*rcp + bb.y;
      float r2 = (a.z + o.z)*rcp + bb.z;
      float r3 = (a.w + o.w)*rcp + bb.w;
      uint2 st; st.x = pack_bf2(r0, r1); st.y = pack_bf2(r2, r3);
      *(uint2*)(outb + (size_t)n*512 + f4) = st;
    }
  }
}

// ---------------- GAT aggregation, 1 head (F=64), bf16 in/out ----------------
__global__ __launch_bounds__(256) void k_gatagg1(const __bf16* __restrict__ hb,
    const float* __restrict__ ssrc, const float* __restrict__ sdst,
    const int* __restrict__ rowptr, const int* __restrict__ colA,
    const float* __restrict__ bias, __bf16* __restrict__ outb){
  int n = blockIdx.x;
  int t = threadIdx.x;
  __shared__ int ecol[CAP];
  __shared__ float p[CAP];
  __shared__ float racc[8][64];
  __shared__ float dhv1, mh1, sds;
  int base = rowptr[n];
  int deg = rowptr[n+1] - base;
  if (t == 0) sds = sdst[n];
  __syncthreads();
  int g = t >> 5, l = t & 31;
  if (deg <= CAP){
    if (t < deg){
      int c = colA[base + t];
      ecol[t] = c;
      float sc = ssrc[c] + sds;
      p[t] = sc > 0.f ? sc : 0.2f*sc;
    }
    __syncthreads();
    if (t < 64){
      float m = -1e30f;
      for (int e = t; e < deg; e += 64) m = fmaxf(m, p[e]);
      #pragma unroll
      for (int off = 1; off < 64; off <<= 1) m = fmaxf(m, __shfl_xor(m, off, 64));
      float d = 0.f;
      for (int e = t; e < deg; e += 64){ float xv = __expf(p[e] - m); p[e] = xv; d += xv; }
      #pragma unroll
      for (int off = 1; off < 64; off <<= 1) d += __shfl_xor(d, off, 64);
      if (t == 0) dhv1 = 1.f / (d + 1e-16f);
    }
    __syncthreads();
    float a0 = 0.f, a1 = 0.f;
    for (int e = g; e < deg; e += 8){
      float pe = p[e];
      unsigned v = *(const unsigned*)(hb + (size_t)ecol[e]*64 + l*2);
      a0 += pe*bf_lo(v); a1 += pe*bf_hi(v);
    }
    racc[g][l*2] = a0; racc[g][l*2+1] = a1;
    __syncthreads();
    if (t < 32){
      float s0 = 0.f, s1 = 0.f;
      #pragma unroll
      for (int g2 = 0; g2 < 8; g2++){ s0 += racc[g2][t*2]; s1 += racc[g2][t*2+1]; }
      float rcp = dhv1;
      float o0 = s0*rcp + bias[t*2], o1 = s1*rcp + bias[t*2+1];
      *(unsigned*)(outb + (size_t)n*64 + t*2) = pack_bf2(o0, o1);
    }
  } else {
    if (t < 64){
      float m = -1e30f;
      for (int e = t; e < deg; e += 64){
        int c = colA[base + e];
        float sc = ssrc[c] + sds;
        sc = sc > 0.f ? sc : 0.2f*sc;
        m = fmaxf(m, sc);
      }
      #pragma unroll
      for (int off = 1; off < 64; off <<= 1) m = fmaxf(m, __shfl_xor(m, off, 64));
      if (t == 0) mh1 = m;
    }
    __syncthreads();
    if (t < 64){
      float d = 0.f;
      for (int e = t; e < deg; e += 64){
        int c = colA[base + e];
        float sc = ssrc[c] + sds;
        sc = sc > 0.f ? sc : 0.2f*sc;
        d += __expf(sc - mh1);
      }
      #pragma unroll
      for (int off = 1; off < 64; off <<= 1) d += __shfl_xor(d, off, 64);
      if (t == 0) dhv1 = 1.f / (d + 1e-16f);
    }
    __syncthreads();
    float a0 = 0.f, a1 = 0.f;
    float mm = mh1;
    for (int e = g; e < deg; e += 8){
      int c = colA[base + e];
      float sc = ssrc[c] + sds;
      sc = sc > 0.f ? sc : 0.2f*sc;
      float pe = __expf(sc - mm);
      unsigned v = *(const unsigned*)(hb + (size_t)c*64 + l*2);
      a0 += pe*bf_lo(v); a1 += pe*bf_hi(v);
    }
    racc[g][l*2] = a0; racc[g][l*2+1] = a1;
    __syncthreads();
    if (t < 32){
      float s0 = 0.f, s1 = 0.f;
      #pragma unroll
      for (int g2 = 0; g2 < 8; g2++){ s0 += racc[g2][t*2]; s1 += racc[g2][t*2+1]; }
      float rcp = dhv1;
      float o0 = s0*rcp + bias[t*2], o1 = s1*rcp + bias[t*2+1];
      *(unsigned*)(outb + (size_t)n*64 + t*2) = pack_bf2(o0, o1);
    }
  }
}

// ---------------- BatchNorm stats: single kernel, last-block final reduce ----------------
__global__ __launch_bounds__(256) void k_bnstat(const __bf16* __restrict__ xb,
    float* __restrict__ partial, float* __restrict__ sum, float* __restrict__ sumsq,
    int F, int* __restrict__ done){
  int t = threadIdx.x;
  int OCT = F >> 3;
  int RPB = 256 / OCT;
  int o = t & (OCT - 1), r = t / OCT;
  int NB = gridDim.x;
  float s[8] = {}, q[8] = {};
  int step = NB * RPB;
  for (int n = blockIdx.x*RPB + r; n < NODES; n += step){
    uint4 v = *(const uint4*)(xb + (size_t)n*F + o*8);
    unsigned vv[4] = {v.x, v.y, v.z, v.w};
    #pragma unroll
    for (int j = 0; j < 4; j++){
      float lo = bf_lo(vv[j]), hi = bf_hi(vv[j]);
      s[2*j]   += lo; q[2*j]   += lo*lo;
      s[2*j+1] += hi; q[2*j+1] += hi*hi;
    }
  }
  __shared__ float red[256][17];
  #pragma unroll
  for (int j = 0; j < 8; j++){ red[t][j] = s[j]; red[t][8+j] = q[j]; }
  __syncthreads();
  for (int st = RPB >> 1; st > 0; st >>= 1){
    if (r < st){
      #pragma unroll
      for (int j = 0; j < 16; j++) red[t][j] += red[t + st*OCT][j];
    }
    __syncthreads();
  }
  if (r == 0){
    #pragma unroll
    for (int j = 0; j < 8; j++){
      partial[(size_t)(o*8 + j)*NB + blockIdx.x]     = red[t][j];
      partial[(size_t)(F + o*8 + j)*NB + blockIdx.x] = red[t][8 + j];
    }
  }
  __threadfence();
  __shared__ int lastf;
  if (t == 0) lastf = (atomicAdd(done, 1) == NB - 1);
  __syncthreads();
  if (!lastf) return;
  __threadfence();
  int rows = 2*F;
  int nb4 = NB >> 2;
  for (int row = t; row < rows; row += 256){
    const float4* pr = (const float4*)(partial + (size_t)row*NB);
    float a = 0.f;
    for (int i = 0; i < nb4; i++){ float4 v = pr[i]; a += (v.x + v.y) + (v.z + v.w); }
    if (row < F) sum[row] = a; else sumsq[row - F] = a;
  }
}

// ---------------- BN(inline) + ELU + optional residual, bf16->bf16 ----------------
__global__ __launch_bounds__(256) void k_bnapply_b(const __bf16* __restrict__ xb,
    const float* __restrict__ sum, const float* __restrict__ sumsq,
    const float* __restrict__ g, const float* __restrict__ b,
    const __bf16* __restrict__ res, __bf16* __restrict__ y, int rows){
  int t = threadIdx.x;
  float2 sm = *(const float2*)(sum + t*2);
  float2 sq = *(const float2*)(sumsq + t*2);
  float2 gg = *(const float2*)(g + t*2);
  float2 bb = *(const float2*)(b + t*2);
  const float inv_n = 1.f / (float)NODES;
  float m0 = sm.x*inv_n, m1 = sm.y*inv_n;
  float v0 = sq.x*inv_n - m0*m0, v1 = sq.y*inv_n - m1*m1;
  float sc0 = gg.x * rsqrtf(v0 + 1e-5f), sc1 = gg.y * rsqrtf(v1 + 1e-5f);
  float sh0 = bb.x - m0*sc0, sh1 = bb.y - m1*sc1;
  int n0 = blockIdx.x * rows;
  for (int r = 0; r < rows; r++){
    int n = n0 + r;
    if (n >= NODES) break;
    size_t off = (size_t)n*512 + t*2;
    unsigned v = *(const unsigned*)(xb + off);
    float o0 = elu_f(bf_lo(v)*sc0 + sh0);
    float o1 = elu_f(bf_hi(v)*sc1 + sh1);
    if (res){
      unsigned rv = *(const unsigned*)(res + off);
      o0 += bf_lo(rv); o1 += bf_hi(rv);
    }
    *(unsigned*)(y + off) = pack_bf2(o0, o1);
  }
}

// ---------------- BN + ELU + LayerNorm for layer 2 (F=64), bf16 in, fp32 out ----------------
__global__ void k_bn_elu_ln_b(const __bf16* __restrict__ xb, const float* __restrict__ sum,
    const float* __restrict__ sumsq, const float* __restrict__ g, const float* __restrict__ b,
    const float* __restrict__ lg, const float* __restrict__ lb, float* __restrict__ y){
  int t = threadIdx.x;
  int l = t & 31, sub = t >> 5;
  int n = blockIdx.x*8 + sub;
  float2 sm = *(const float2*)(sum + l*2);
  float2 sq = *(const float2*)(sumsq + l*2);
  float2 gg = *(const float2*)(g + l*2);
  float2 bb = *(const float2*)(b + l*2);
  const float inv_n = 1.f / (float)NODES;
  float m0 = sm.x*inv_n, m1 = sm.y*inv_n;
  float va0 = sq.x*inv_n - m0*m0, va1 = sq.y*inv_n - m1*m1;
  float sc0 = gg.x * rsqrtf(va0 + 1e-5f), sc1 = gg.y * rsqrtf(va1 + 1e-5f);
  float sh0 = bb.x - m0*sc0, sh1 = bb.y - m1*sc1;
  unsigned v = *(const unsigned*)(xb + (size_t)n*64 + l*2);
  float x0 = elu_f(bf_lo(v)*sc0 + sh0);
  float x1 = elu_f(bf_hi(v)*sc1 + sh1);
  float s = x0 + x1;
  #pragma unroll
  for (int off = 1; off < 32; off <<= 1) s += __shfl_xor(s, off, 64);
  float mean = s * (1.f/64.f);
  float d0 = x0 - mean, d1 = x1 - mean;
  float qq = d0*d0 + d1*d1;
  #pragma unroll
  for (int off = 1; off < 32; off <<= 1) qq += __shfl_xor(qq, off, 64);
  float var = qq * (1.f/64.f);
  float inv = rsqrtf(var + 1e-5f);
  float2 o = make_float2(d0*inv*lg[l*2] + lb[l*2], d1*inv*lg[l*2+1] + lb[l*2+1]);
  *(float2*)(y + (size_t)n*64 + l*2) = o;
}

// ---------------- global mean pool + MLP head fused (last-block) ----------------
static __device__ int lbound(const int* a, int n, int v){
  int lo = 0, hi = n;
  while (lo < hi){ int mid = (lo + hi) >> 1; if (a[mid] < v) lo = mid + 1; else hi = mid; }
  return lo;
}

__global__ __launch_bounds__(256) void k_poolhead(const float* __restrict__ xl,
    const int* __restrict__ batch, float* __restrict__ pooled,
    const float* __restrict__ w1, const float* __restrict__ b1,
    const float* __restrict__ w2, const float* __restrict__ b2,
    float* __restrict__ out, int* __restrict__ done){
  int g = blockIdx.x;
  int t = threadIdx.x;
  int lo = lbound(batch, NODES, g);
  int hi = lbound(batch, NODES, g+1);
  int f = t & 63, grp = t >> 6;
  float acc = 0.f;
  for (int n = lo + grp; n < hi; n += 4) acc += xl[(size_t)n*DH + f];
  __shared__ float red[4][64];
  red[grp][f] = acc;
  __syncthreads();
  if (grp == 0){
    float s = red[0][f] + red[1][f] + red[2][f] + red[3][f];
    int cnt = hi - lo;
    pooled[g*DH + f] = s / fmaxf((float)cnt, 1.f);
  }
  __threadfence();
  __shared__ int lastf;
  if (t == 0) lastf = (atomicAdd(done, 1) == NGRAPH - 1);
  __syncthreads();
  if (!lastf) return;
  __threadfence();
  if (t >= NGRAPH) return;
  const float* pd = pooled + t*DH;
  float hdd[32];
  for (int j = 0; j < 32; j++){
    float s = b1[j];
    for (int d = 0; d < DH; d++) s += pd[d]*w1[d*32 + j];
    hdd[j] = elu_f(s);
  }
  float l0 = b2[0], l1 = b2[1];
  for (int j = 0; j < 32; j++){ l0 += hdd[j]*w2[j*2]; l1 += hdd[j]*w2[j*2 + 1]; }
  float m = fmaxf(l0, l1);
  float lse = m + logf(expf(l0 - m) + expf(l1 - m));
  out[t*2]     = l0 - lse;
  out[t*2 + 1] = l1 - lse;
}

extern "C" void kernel_launch(void* const* d_in, const int* in_sizes, int n_in,
                              void* d_out, int out_size, void* d_ws, size_t ws_size,
                              hipStream_t stream){
  const float* x    = (const float*)d_in[0];
  const int*   ei   = (const int*)d_in[1];
  const int*   batch= (const int*)d_in[2];
  const float* W0   = (const float*)d_in[3];
  const float* as0  = (const float*)d_in[4];
  const float* ad0  = (const float*)d_in[5];
  const float* b0   = (const float*)d_in[6];
  const float* W1   = (const float*)d_in[7];
  const float* as1  = (const float*)d_in[8];
  const float* ad1  = (const float*)d_in[9];
  const float* b1   = (const float*)d_in[10];
  const float* W2   = (const float*)d_in[11];
  const float* as2  = (const float*)d_in[12];
  const float* ad2  = (const float*)d_in[13];
  const float* b2   = (const float*)d_in[14];
  const float* bn0g = (const float*)d_in[15];
  const float* bn0b = (const float*)d_in[16];
  const float* bn1g = (const float*)d_in[17];
  const float* bn1b = (const float*)d_in[18];
  const float* bn2g = (const float*)d_in[19];
  const float* bn2b = (const float*)d_in[20];
  const float* lng  = (const float*)d_in[21];
  const float* lnb  = (const float*)d_in[22];
  const float* fc1w = (const float*)d_in[23];
  const float* fc1b = (const float*)d_in[24];
  const float* fc2w = (const float*)d_in[25];
  const float* fc2b = (const float*)d_in[26];
  float* out = (float*)d_out;

  char* w = (char*)d_ws;
  auto alloc = [&](size_t bytes) -> char* {
    char* p = w; w += (bytes + 255) & ~(size_t)255; return p;
  };
  __bf16* xb0   = (__bf16*)alloc((size_t)NODES*DIN*2);
  __bf16* hbuf  = (__bf16*)alloc((size_t)NODES*512*2);
  __bf16* gbuf  = (__bf16*)alloc((size_t)NODES*512*2);
  __bf16* x1b   = (__bf16*)alloc((size_t)NODES*512*2);
  __bf16* x2b   = (__bf16*)alloc((size_t)NODES*512*2);
  __bf16* Wt0   = (__bf16*)alloc((size_t)TW0*2);
  __bf16* Wt1   = (__bf16*)alloc((size_t)TW1*2);
  __bf16* Wt2   = (__bf16*)alloc((size_t)TW2*2);
  float*  ssrc  = (float*)alloc((size_t)NODES*8*4);
  float*  sdst  = (float*)alloc((size_t)NODES*8*4);
  float*  xl    = (float*)alloc((size_t)NODES*DH*4);
  float*  pooled= (float*)alloc(NGRAPH*DH*4);
  int*    rowptr= (int*)alloc((NODES+1)*4);
  int*    colA  = (int*)alloc((size_t)ETOT*4);
  float*  partial=(float*)alloc((size_t)2*512*512*4);
  float*  sum0  = (float*)alloc(512*4);
  float*  sq0   = (float*)alloc(512*4);
  float*  sum1  = (float*)alloc(512*4);
  float*  sq1   = (float*)alloc(512*4);
  float*  sum2  = (float*)alloc(64*4);
  float*  sq2   = (float*)alloc(64*4);
  char* zbase  = w;
  int*   deg   = (int*)alloc(NODES*4);
  int*   cursor= (int*)alloc(NODES*4);
  int*   dones = (int*)alloc(8*4);   // done counters: cs, bn0, bn1, bn2, ph
  size_t zbytes = (size_t)(w - zbase);
  hipMemsetAsync(zbase, 0, zbytes, stream);

  const int eb = (ETOT + 255)/256;
  k_countscan<<<eb, 256, 0, stream>>>(ei, deg, rowptr, &dones[0]);
  k_fill<<<eb, 256, 0, stream>>>(ei, rowptr, cursor, colA);

  const int prep_total = NCAST4 + TW0 + TW1 + TW2;
  k_prep<<<(prep_total + 255)/256, 256, 0, stream>>>(x, xb0, W0, W1, W2, Wt0, Wt1, Wt2);

  const int mb128 = (NODES + 127)/128;
  const int nb8 = (NODES + 7)/8;

  // ---- layer 0: 256 -> 8x64 ----
  k_gemm_bf16<<<dim3(4, mb128), 256, 0, stream>>>(xb0, Wt0, hbuf, as0, ad0, ssrc, sdst, 8, NODES, 512, DIN);
  k_gatagg8<<<NODES, 256, 0, stream>>>(hbuf, ssrc, sdst, rowptr, colA, b0, gbuf);
  k_bnstat<<<512, 256, 0, stream>>>(gbuf, partial, sum0, sq0, 512, &dones[1]);
  k_bnapply_b<<<nb8, 256, 0, stream>>>(gbuf, sum0, sq0, bn0g, bn0b, nullptr, x1b, 8);

  // ---- layer 1: 512 -> 8x64, residual ----
  k_gemm_bf16<<<dim3(4, mb128), 256, 0, stream>>>(x1b, Wt1, hbuf, as1, ad1, ssrc, sdst, 8, NODES, 512, 512);
  k_gatagg8<<<NODES, 256, 0, stream>>>(hbuf, ssrc, sdst, rowptr, colA, b1, gbuf);
  k_bnstat<<<512, 256, 0, stream>>>(gbuf, partial, sum1, sq1, 512, &dones[2]);
  k_bnapply_b<<<nb8, 256, 0, stream>>>(gbuf, sum1, sq1, bn1g, bn1b, x1b, x2b, 8);

  // ---- layer 2: 512 -> 1x64 ----
  k_gemm_bf16<<<dim3(1, mb128), 256, 0, stream>>>(x2b, Wt2, hbuf, as2, ad2, ssrc, sdst, 1, NODES, 64, 512);
  k_gatagg1<<<NODES, 256, 0, stream>>>(hbuf, ssrc, sdst, rowptr, colA, b2, gbuf);
  k_bnstat<<<256, 256, 0, stream>>>(gbuf, partial, sum2, sq2, 64, &dones[3]);
  k_bn_elu_ln_b<<<nb8, 256, 0, stream>>>(gbuf, sum2, sq2, bn2g, bn2b, lng, lnb, xl);

  k_poolhead<<<NGRAPH, 256, 0, stream>>>(xl, batch, pooled, fc1w, fc1b, fc2w, fc2b, out, &dones[4]);
}

// Round 8
// 744.793 us; speedup vs baseline: 1.5768x; 1.5768x over previous
//
#include <hip/hip_runtime.h>
#include <math.h>

#define NODES 30000
#define NEDGE 480000
#define ETOT  (NODES + NEDGE)
#define NGRAPH 30
#define DIN 256
#define DH 64
#define CAP 128

typedef __bf16 bf16x8 __attribute__((ext_vector_type(8)));
typedef float  f32x4  __attribute__((ext_vector_type(4)));

static __device__ __forceinline__ float elu_f(float x){ return x > 0.f ? x : expm1f(x); }
static __device__ __forceinline__ float bf_lo(unsigned v){ return __uint_as_float(v << 16); }
static __device__ __forceinline__ float bf_hi(unsigned v){ return __uint_as_float(v & 0xffff0000u); }
static __device__ __forceinline__ unsigned pack_bf2(float a, float b){
  __bf16 ob[2] = {(__bf16)a, (__bf16)b};
  return *(unsigned*)ob;
}

// ---------------- CSR build (by destination) ----------------
__global__ void k_count(const int* __restrict__ ei, int* __restrict__ deg){
  int e = blockIdx.x*256 + threadIdx.x;
  if (e >= ETOT) return;
  int dst = (e < NEDGE) ? ei[NEDGE + e] : (e - NEDGE);
  atomicAdd(&deg[dst], 1);
}

__global__ void k_scan(const int* __restrict__ deg, int* __restrict__ rowptr){
  __shared__ int s[1024];
  int t = threadIdx.x;
  const int CH = (NODES + 1023) / 1024;
  int base = t * CH;
  int local = 0;
  for (int i = 0; i < CH; i++){ int idx = base + i; if (idx < NODES) local += deg[idx]; }
  s[t] = local; __syncthreads();
  for (int off = 1; off < 1024; off <<= 1){
    int v = (t >= off) ? s[t - off] : 0;
    __syncthreads();
    s[t] += v;
    __syncthreads();
  }
  int run = s[t] - local;
  for (int i = 0; i < CH; i++){
    int idx = base + i;
    if (idx < NODES){ rowptr[idx] = run; run += deg[idx]; }
  }
  if (t == 1023) rowptr[NODES] = s[1023];
}

__global__ void k_fill(const int* __restrict__ ei, const int* __restrict__ rowptr,
                       int* __restrict__ cursor, int* __restrict__ colA){
  int e = blockIdx.x*256 + threadIdx.x;
  if (e >= ETOT) return;
  int src, dst;
  if (e < NEDGE){ src = ei[e]; dst = ei[NEDGE + e]; }
  else          { src = e - NEDGE; dst = src; }
  int pos = atomicAdd(&cursor[dst], 1);
  colA[rowptr[dst] + pos] = src;
}

// ---------------- fused input cast + all weight transposes ----------------
#define NCAST4 (NODES*DIN/4)
#define TW0 (512*256)
#define TW1 (512*512)
#define TW2 (64*512)
__global__ void k_prep(const float* __restrict__ x, __bf16* __restrict__ xb0,
                       const float* __restrict__ W0, const float* __restrict__ W1,
                       const float* __restrict__ W2, __bf16* __restrict__ Wt0,
                       __bf16* __restrict__ Wt1, __bf16* __restrict__ Wt2){
  int idx = blockIdx.x*256 + threadIdx.x;
  if (idx < NCAST4){
    float4 v = ((const float4*)x)[idx];
    __bf16 o[4] = {(__bf16)v.x, (__bf16)v.y, (__bf16)v.z, (__bf16)v.w};
    *(uint2*)(xb0 + (size_t)idx*4) = *(const uint2*)o;
    return;
  }
  int j = idx - NCAST4;
  if (j < TW0){
    int n = j >> 8, k = j & 255;
    Wt0[j] = (__bf16)W0[(size_t)k*512 + n];
  } else if (j < TW0 + TW1){
    int j1 = j - TW0;
    int n = j1 >> 9, k = j1 & 511;
    Wt1[j1] = (__bf16)W1[(size_t)k*512 + n];
  } else if (j < TW0 + TW1 + TW2){
    int j2 = j - TW0 - TW1;
    int n = j2 >> 9, k = j2 & 511;
    Wt2[j2] = (__bf16)W2[(size_t)k*64 + n];
  }
}

// ---------------- bf16 MFMA GEMM + fused attention scores ----------------
#define LSTR 72
__global__ __launch_bounds__(256) void k_gemm_bf16(const __bf16* __restrict__ A,
    const __bf16* __restrict__ Bt, __bf16* __restrict__ C,
    const float* __restrict__ asrc, const float* __restrict__ adst,
    float* __restrict__ ssrc, float* __restrict__ sdst, int heads,
    int M, int N, int K){
  __shared__ __align__(16) __bf16 As[128*LSTR];
  __shared__ __align__(16) __bf16 Bs[128*LSTR];
  int tid  = threadIdx.x;
  int lane = tid & 63, wave = tid >> 6;
  int wr = wave >> 1, wc = wave & 1;
  int q = lane >> 4, r = lane & 15;
  int rowBase = blockIdx.y * 128, colBase = blockIdx.x * 128;
  f32x4 acc[4][4] = {};
  for (int k0 = 0; k0 < K; k0 += 64){
    #pragma unroll
    for (int p = 0; p < 4; p++){
      int lin = p*256 + tid;
      int rr = lin >> 3, ko = (lin & 7) * 8;
      uint4 va = make_uint4(0,0,0,0);
      int gr = rowBase + rr;
      if (gr < M) va = *(const uint4*)(A + (size_t)gr*K + k0 + ko);
      *(uint4*)(&As[rr*LSTR + ko]) = va;
      uint4 vb = make_uint4(0,0,0,0);
      int gn = colBase + rr;
      if (gn < N) vb = *(const uint4*)(Bt + (size_t)gn*K + k0 + ko);
      *(uint4*)(&Bs[rr*LSTR + ko]) = vb;
    }
    __syncthreads();
    #pragma unroll
    for (int kk = 0; kk < 2; kk++){
      bf16x8 af[4], bfr[4];
      #pragma unroll
      for (int i = 0; i < 4; i++) af[i]  = *(const bf16x8*)(&As[(wr*64 + i*16 + r)*LSTR + kk*32 + q*8]);
      #pragma unroll
      for (int j = 0; j < 4; j++) bfr[j] = *(const bf16x8*)(&Bs[(wc*64 + j*16 + r)*LSTR + kk*32 + q*8]);
      #pragma unroll
      for (int i = 0; i < 4; i++)
        #pragma unroll
        for (int j = 0; j < 4; j++)
          acc[i][j] = __builtin_amdgcn_mfma_f32_16x16x32_bf16(af[i], bfr[j], acc[i][j], 0, 0, 0);
    }
    __syncthreads();
  }
  #pragma unroll
  for (int i = 0; i < 4; i++){
    #pragma unroll
    for (int j = 0; j < 4; j++){
      int col = colBase + wc*64 + j*16 + r;
      if (col >= N) continue;
      #pragma unroll
      for (int v = 0; v < 4; v++){
        int row = rowBase + wr*64 + i*16 + q*4 + v;
        if (row < M) C[(size_t)row*N + col] = (__bf16)acc[i][j][v];
      }
    }
  }
  // fused attention scores: head hb owns cols [hb*64, hb*64+64)
  int colW = colBase + wc*64;
  if (colW < N){
    int hb = colW >> 6;
    float a_s[4], a_d[4];
    #pragma unroll
    for (int j = 0; j < 4; j++){
      a_s[j] = asrc[hb*64 + j*16 + r];
      a_d[j] = adst[hb*64 + j*16 + r];
    }
    #pragma unroll
    for (int i = 0; i < 4; i++){
      #pragma unroll
      for (int v = 0; v < 4; v++){
        float s1 = 0.f, s2 = 0.f;
        #pragma unroll
        for (int j = 0; j < 4; j++){
          float av = acc[i][j][v];
          s1 += av * a_s[j];
          s2 += av * a_d[j];
        }
        #pragma unroll
        for (int off = 1; off < 16; off <<= 1){
          s1 += __shfl_xor(s1, off, 64);
          s2 += __shfl_xor(s2, off, 64);
        }
        if (r == 0){
          int row = rowBase + wr*64 + i*16 + q*4 + v;
          if (row < M){
            ssrc[(size_t)row*heads + hb] = s1;
            sdst[(size_t)row*heads + hb] = s2;
          }
        }
      }
    }
  }
}

// ---------------- GAT aggregation, 8 heads; 4 feats/thread, 2 edges/round ----------------
__global__ __launch_bounds__(256) void k_gatagg8(const __bf16* __restrict__ hb,
    const float* __restrict__ ssrc, const float* __restrict__ sdst,
    const int* __restrict__ rowptr, const int* __restrict__ colA,
    const float* __restrict__ bias, __bf16* __restrict__ outb){
  int n = blockIdx.x;
  int t = threadIdx.x;
  __shared__ int ecol[CAP];
  __shared__ float p[CAP][9];
  __shared__ float racc[512];
  __shared__ float dhv[8], sdsh[8], mh[8];
  int base = rowptr[n];
  int deg = rowptr[n+1] - base;
  if (t < 8) sdsh[t] = sdst[(size_t)n*8 + t];
  __syncthreads();
  int g = t >> 5, l = t & 31;
  int half = t >> 7;
  int tf = t & 127;
  int f4 = tf * 4;
  int hh4 = tf >> 4;
  if (deg <= CAP){
    if (t < deg){
      int c = colA[base + t];
      ecol[t] = c;
      const float4* sp = (const float4*)(ssrc + (size_t)c*8);
      float4 s0 = sp[0], s1 = sp[1];
      float v;
      v = s0.x + sdsh[0]; p[t][0] = v > 0.f ? v : 0.2f*v;
      v = s0.y + sdsh[1]; p[t][1] = v > 0.f ? v : 0.2f*v;
      v = s0.z + sdsh[2]; p[t][2] = v > 0.f ? v : 0.2f*v;
      v = s0.w + sdsh[3]; p[t][3] = v > 0.f ? v : 0.2f*v;
      v = s1.x + sdsh[4]; p[t][4] = v > 0.f ? v : 0.2f*v;
      v = s1.y + sdsh[5]; p[t][5] = v > 0.f ? v : 0.2f*v;
      v = s1.z + sdsh[6]; p[t][6] = v > 0.f ? v : 0.2f*v;
      v = s1.w + sdsh[7]; p[t][7] = v > 0.f ? v : 0.2f*v;
    }
    __syncthreads();
    {
      float m = -1e30f;
      for (int e = l; e < deg; e += 32) m = fmaxf(m, p[e][g]);
      #pragma unroll
      for (int off = 1; off < 32; off <<= 1) m = fmaxf(m, __shfl_xor(m, off, 64));
      float d = 0.f;
      for (int e = l; e < deg; e += 32){ float xv = __expf(p[e][g] - m); p[e][g] = xv; d += xv; }
      #pragma unroll
      for (int off = 1; off < 32; off <<= 1) d += __shfl_xor(d, off, 64);
      if (l == 0) dhv[g] = 1.f / (d + 1e-16f);
    }
    __syncthreads();
    float4 a = make_float4(0.f, 0.f, 0.f, 0.f);
    int e = half;
    for (; e + 2 < deg; e += 4){
      int c0 = ecol[e], c1 = ecol[e+2];
      float p0 = p[e][hh4], p1 = p[e+2][hh4];
      uint2 v0 = *(const uint2*)(hb + (size_t)c0*512 + f4);
      uint2 v1 = *(const uint2*)(hb + (size_t)c1*512 + f4);
      a.x += p0*bf_lo(v0.x); a.y += p0*bf_hi(v0.x);
      a.z += p0*bf_lo(v0.y); a.w += p0*bf_hi(v0.y);
      a.x += p1*bf_lo(v1.x); a.y += p1*bf_hi(v1.x);
      a.z += p1*bf_lo(v1.y); a.w += p1*bf_hi(v1.y);
    }
    for (; e < deg; e += 2){
      int c = ecol[e];
      float pe = p[e][hh4];
      uint2 v = *(const uint2*)(hb + (size_t)c*512 + f4);
      a.x += pe*bf_lo(v.x); a.y += pe*bf_hi(v.x);
      a.z += pe*bf_lo(v.y); a.w += pe*bf_hi(v.y);
    }
    if (half == 1) *(float4*)&racc[f4] = a;
    __syncthreads();
    if (half == 0){
      float4 o = *(const float4*)&racc[f4];
      float rcp = dhv[hh4];
      float4 bb = *(const float4*)(bias + f4);
      float r0 = (a.x + o.x)*rcp + bb.x;
      float r1 = (a.y + o.y)*rcp + bb.y;
      float r2 = (a.z + o.z)*rcp + bb.z;
      float r3 = (a.w + o.w)*rcp + bb.w;
      uint2 st; st.x = pack_bf2(r0, r1); st.y = pack_bf2(r2, r3);
      *(uint2*)(outb + (size_t)n*512 + f4) = st;
    }
  } else {
    float m = -1e30f;
    for (int e = l; e < deg; e += 32){
      int c = colA[base + e];
      float sc = ssrc[(size_t)c*8 + g] + sdsh[g];
      sc = sc > 0.f ? sc : 0.2f*sc;
      m = fmaxf(m, sc);
    }
    #pragma unroll
    for (int off = 1; off < 32; off <<= 1) m = fmaxf(m, __shfl_xor(m, off, 64));
    if (l == 0) mh[g] = m;
    __syncthreads();
    float d = 0.f;
    float mm = mh[g];
    for (int e = l; e < deg; e += 32){
      int c = colA[base + e];
      float sc = ssrc[(size_t)c*8 + g] + sdsh[g];
      sc = sc > 0.f ? sc : 0.2f*sc;
      d += __expf(sc - mm);
    }
    #pragma unroll
    for (int off = 1; off < 32; off <<= 1) d += __shfl_xor(d, off, 64);
    if (l == 0) dhv[g] = 1.f / (d + 1e-16f);
    __syncthreads();
    float4 a = make_float4(0.f, 0.f, 0.f, 0.f);
    float mhh = mh[hh4];
    float sdd = sdsh[hh4];
    for (int e = half; e < deg; e += 2){
      int c = colA[base + e];
      float sc = ssrc[(size_t)c*8 + hh4] + sdd;
      sc = sc > 0.f ? sc : 0.2f*sc;
      float pe = __expf(sc - mhh);
      uint2 v = *(const uint2*)(hb + (size_t)c*512 + f4);
      a.x += pe*bf_lo(v.x); a.y += pe*bf_hi(v.x);
      a.z += pe*bf_lo(v.y); a.w += pe*bf_hi(v.y);
    }
    if (half == 1) *(float4*)&racc[f4] = a;
    __syncthreads();
    if (half == 0){
      float4 o = *(const float4*)&racc[f4];
      float rcp = dhv[hh4];
      float4 bb = *(const float4*)(bias + f4);
      float r0 = (a.x + o.x)*rcp + bb.x;
      float r1 = (a.y + o.y)*rcp + bb.y;
      float r2 = (a.z + o.z)*rcp + bb.z;
      float r3 = (a.w + o.w)*rcp + bb.w;
      uint2 st; st.x = pack_bf2(r0, r1); st.y = pack_bf2(r2, r3);
      *(uint2*)(outb + (size_t)n*512 + f4) = st;
    }
  }
}

// ---------------- GAT aggregation, 1 head (F=64), bf16 in/out ----------------
__global__ __launch_bounds__(256) void k_gatagg1(const __bf16* __restrict__ hb,
    const float* __restrict__ ssrc, const float* __restrict__ sdst,
    const int* __restrict__ rowptr, const int* __restrict__ colA,
    const float* __restrict__ bias, __bf16* __restrict__ outb){
  int n = blockIdx.x;
  int t = threadIdx.x;
  __shared__ int ecol[CAP];
  __shared__ float p[CAP];
  __shared__ float racc[8][64];
  __shared__ float dhv1, mh1, sds;
  int base = rowptr[n];
  int deg = rowptr[n+1] - base;
  if (t == 0) sds = sdst[n];
  __syncthreads();
  int g = t >> 5, l = t & 31;
  if (deg <= CAP){
    if (t < deg){
      int c = colA[base + t];
      ecol[t] = c;
      float sc = ssrc[c] + sds;
      p[t] = sc > 0.f ? sc : 0.2f*sc;
    }
    __syncthreads();
    if (t < 64){
      float m = -1e30f;
      for (int e = t; e < deg; e += 64) m = fmaxf(m, p[e]);
      #pragma unroll
      for (int off = 1; off < 64; off <<= 1) m = fmaxf(m, __shfl_xor(m, off, 64));
      float d = 0.f;
      for (int e = t; e < deg; e += 64){ float xv = __expf(p[e] - m); p[e] = xv; d += xv; }
      #pragma unroll
      for (int off = 1; off < 64; off <<= 1) d += __shfl_xor(d, off, 64);
      if (t == 0) dhv1 = 1.f / (d + 1e-16f);
    }
    __syncthreads();
    float a0 = 0.f, a1 = 0.f;
    for (int e = g; e < deg; e += 8){
      float pe = p[e];
      unsigned v = *(const unsigned*)(hb + (size_t)ecol[e]*64 + l*2);
      a0 += pe*bf_lo(v); a1 += pe*bf_hi(v);
    }
    racc[g][l*2] = a0; racc[g][l*2+1] = a1;
    __syncthreads();
    if (t < 32){
      float s0 = 0.f, s1 = 0.f;
      #pragma unroll
      for (int g2 = 0; g2 < 8; g2++){ s0 += racc[g2][t*2]; s1 += racc[g2][t*2+1]; }
      float rcp = dhv1;
      float o0 = s0*rcp + bias[t*2], o1 = s1*rcp + bias[t*2+1];
      *(unsigned*)(outb + (size_t)n*64 + t*2) = pack_bf2(o0, o1);
    }
  } else {
    if (t < 64){
      float m = -1e30f;
      for (int e = t; e < deg; e += 64){
        int c = colA[base + e];
        float sc = ssrc[c] + sds;
        sc = sc > 0.f ? sc : 0.2f*sc;
        m = fmaxf(m, sc);
      }
      #pragma unroll
      for (int off = 1; off < 64; off <<= 1) m = fmaxf(m, __shfl_xor(m, off, 64));
      if (t == 0) mh1 = m;
    }
    __syncthreads();
    if (t < 64){
      float d = 0.f;
      for (int e = t; e < deg; e += 64){
        int c = colA[base + e];
        float sc = ssrc[c] + sds;
        sc = sc > 0.f ? sc : 0.2f*sc;
        d += __expf(sc - mh1);
      }
      #pragma unroll
      for (int off = 1; off < 64; off <<= 1) d += __shfl_xor(d, off, 64);
      if (t == 0) dhv1 = 1.f / (d + 1e-16f);
    }
    __syncthreads();
    float a0 = 0.f, a1 = 0.f;
    float mm = mh1;
    for (int e = g; e < deg; e += 8){
      int c = colA[base + e];
      float sc = ssrc[c] + sds;
      sc = sc > 0.f ? sc : 0.2f*sc;
      float pe = __expf(sc - mm);
      unsigned v = *(const unsigned*)(hb + (size_t)c*64 + l*2);
      a0 += pe*bf_lo(v); a1 += pe*bf_hi(v);
    }
    racc[g][l*2] = a0; racc[g][l*2+1] = a1;
    __syncthreads();
    if (t < 32){
      float s0 = 0.f, s1 = 0.f;
      #pragma unroll
      for (int g2 = 0; g2 < 8; g2++){ s0 += racc[g2][t*2]; s1 += racc[g2][t*2+1]; }
      float rcp = dhv1;
      float o0 = s0*rcp + bias[t*2], o1 = s1*rcp + bias[t*2+1];
      *(unsigned*)(outb + (size_t)n*64 + t*2) = pack_bf2(o0, o1);
    }
  }
}

// ---------------- BatchNorm stats, two-stage, NO atomics ----------------
__global__ __launch_bounds__(256) void k_bnstat1(const __bf16* __restrict__ xb,
    float* __restrict__ partial, int F){
  int t = threadIdx.x;
  int OCT = F >> 3;
  int RPB = 256 / OCT;
  int o = t & (OCT - 1), r = t / OCT;
  int NB = gridDim.x;
  float s[8] = {}, q[8] = {};
  int step = NB * RPB;
  for (int n = blockIdx.x*RPB + r; n < NODES; n += step){
    uint4 v = *(const uint4*)(xb + (size_t)n*F + o*8);
    unsigned vv[4] = {v.x, v.y, v.z, v.w};
    #pragma unroll
    for (int j = 0; j < 4; j++){
      float lo = bf_lo(vv[j]), hi = bf_hi(vv[j]);
      s[2*j]   += lo; q[2*j]   += lo*lo;
      s[2*j+1] += hi; q[2*j+1] += hi*hi;
    }
  }
  __shared__ float red[256][17];
  #pragma unroll
  for (int j = 0; j < 8; j++){ red[t][j] = s[j]; red[t][8+j] = q[j]; }
  __syncthreads();
  for (int st = RPB >> 1; st > 0; st >>= 1){
    if (r < st){
      #pragma unroll
      for (int j = 0; j < 16; j++) red[t][j] += red[t + st*OCT][j];
    }
    __syncthreads();
  }
  if (r == 0){
    #pragma unroll
    for (int j = 0; j < 8; j++){
      partial[(size_t)(o*8 + j)*NB + blockIdx.x]     = red[t][j];
      partial[(size_t)(F + o*8 + j)*NB + blockIdx.x] = red[t][8 + j];
    }
  }
}

__global__ void k_bnstat2(const float* __restrict__ partial, float* __restrict__ sum,
                          float* __restrict__ sumsq, int F, int NB){
  int row = blockIdx.x;
  int t = threadIdx.x;
  float a = 0.f;
  for (int i = t; i < NB; i += 64) a += partial[(size_t)row*NB + i];
  #pragma unroll
  for (int off = 1; off < 64; off <<= 1) a += __shfl_xor(a, off, 64);
  if (t == 0){
    if (row < F) sum[row] = a;
    else         sumsq[row - F] = a;
  }
}

// ---------------- BN(inline) + ELU + optional residual, bf16->bf16 ----------------
__global__ __launch_bounds__(256) void k_bnapply_b(const __bf16* __restrict__ xb,
    const float* __restrict__ sum, const float* __restrict__ sumsq,
    const float* __restrict__ g, const float* __restrict__ b,
    const __bf16* __restrict__ res, __bf16* __restrict__ y, int rows){
  int t = threadIdx.x;
  float2 sm = *(const float2*)(sum + t*2);
  float2 sq = *(const float2*)(sumsq + t*2);
  float2 gg = *(const float2*)(g + t*2);
  float2 bb = *(const float2*)(b + t*2);
  const float inv_n = 1.f / (float)NODES;
  float m0 = sm.x*inv_n, m1 = sm.y*inv_n;
  float v0 = sq.x*inv_n - m0*m0, v1 = sq.y*inv_n - m1*m1;
  float sc0 = gg.x * rsqrtf(v0 + 1e-5f), sc1 = gg.y * rsqrtf(v1 + 1e-5f);
  float sh0 = bb.x - m0*sc0, sh1 = bb.y - m1*sc1;
  int n0 = blockIdx.x * rows;
  for (int r = 0; r < rows; r++){
    int n = n0 + r;
    if (n >= NODES) break;
    size_t off = (size_t)n*512 + t*2;
    unsigned v = *(const unsigned*)(xb + off);
    float o0 = elu_f(bf_lo(v)*sc0 + sh0);
    float o1 = elu_f(bf_hi(v)*sc1 + sh1);
    if (res){
      unsigned rv = *(const unsigned*)(res + off);
      o0 += bf_lo(rv); o1 += bf_hi(rv);
    }
    *(unsigned*)(y + off) = pack_bf2(o0, o1);
  }
}

// ---------------- BN + ELU + LayerNorm for layer 2 (F=64), bf16 in, fp32 out ----------------
__global__ void k_bn_elu_ln_b(const __bf16* __restrict__ xb, const float* __restrict__ sum,
    const float* __restrict__ sumsq, const float* __restrict__ g, const float* __restrict__ b,
    const float* __restrict__ lg, const float* __restrict__ lb, float* __restrict__ y){
  int t = threadIdx.x;
  int l = t & 31, sub = t >> 5;
  int n = blockIdx.x*8 + sub;
  float2 sm = *(const float2*)(sum + l*2);
  float2 sq = *(const float2*)(sumsq + l*2);
  float2 gg = *(const float2*)(g + l*2);
  float2 bb = *(const float2*)(b + l*2);
  const float inv_n = 1.f / (float)NODES;
  float m0 = sm.x*inv_n, m1 = sm.y*inv_n;
  float va0 = sq.x*inv_n - m0*m0, va1 = sq.y*inv_n - m1*m1;
  float sc0 = gg.x * rsqrtf(va0 + 1e-5f), sc1 = gg.y * rsqrtf(va1 + 1e-5f);
  float sh0 = bb.x - m0*sc0, sh1 = bb.y - m1*sc1;
  unsigned v = *(const unsigned*)(xb + (size_t)n*64 + l*2);
  float x0 = elu_f(bf_lo(v)*sc0 + sh0);
  float x1 = elu_f(bf_hi(v)*sc1 + sh1);
  float s = x0 + x1;
  #pragma unroll
  for (int off = 1; off < 32; off <<= 1) s += __shfl_xor(s, off, 64);
  float mean = s * (1.f/64.f);
  float d0 = x0 - mean, d1 = x1 - mean;
  float qq = d0*d0 + d1*d1;
  #pragma unroll
  for (int off = 1; off < 32; off <<= 1) qq += __shfl_xor(qq, off, 64);
  float var = qq * (1.f/64.f);
  float inv = rsqrtf(var + 1e-5f);
  float2 o = make_float2(d0*inv*lg[l*2] + lb[l*2], d1*inv*lg[l*2+1] + lb[l*2+1]);
  *(float2*)(y + (size_t)n*64 + l*2) = o;
}

// ---------------- global mean pool ----------------
static __device__ int lbound(const int* a, int n, int v){
  int lo = 0, hi = n;
  while (lo < hi){ int mid = (lo + hi) >> 1; if (a[mid] < v) lo = mid + 1; else hi = mid; }
  return lo;
}

__global__ void k_pool(const float* __restrict__ xl, const int* __restrict__ batch,
                       float* __restrict__ pooled){
  int g = blockIdx.x;
  int t = threadIdx.x;
  int lo = lbound(batch, NODES, g);
  int hi = lbound(batch, NODES, g+1);
  int f = t & 63, grp = t >> 6;
  float acc = 0.f;
  for (int n = lo + grp; n < hi; n += 4) acc += xl[(size_t)n*DH + f];
  __shared__ float red[4][64];
  red[grp][f] = acc;
  __syncthreads();
  if (grp == 0){
    float s = red[0][f] + red[1][f] + red[2][f] + red[3][f];
    int cnt = hi - lo;
    pooled[g*DH + f] = s / fmaxf((float)cnt, 1.f);
  }
}

// ---------------- MLP head + log_softmax ----------------
__global__ void k_head(const float* __restrict__ pooled, const float* __restrict__ w1,
                       const float* __restrict__ b1, const float* __restrict__ w2,
                       const float* __restrict__ b2, float* __restrict__ out){
  int g = threadIdx.x;
  if (g >= NGRAPH) return;
  const float* pd = pooled + g*DH;
  float hdd[32];
  for (int j = 0; j < 32; j++){
    float s = b1[j];
    for (int d = 0; d < DH; d++) s += pd[d]*w1[d*32 + j];
    hdd[j] = elu_f(s);
  }
  float l0 = b2[0], l1 = b2[1];
  for (int j = 0; j < 32; j++){ l0 += hdd[j]*w2[j*2]; l1 += hdd[j]*w2[j*2 + 1]; }
  float m = fmaxf(l0, l1);
  float lse = m + logf(expf(l0 - m) + expf(l1 - m));
  out[g*2]     = l0 - lse;
  out[g*2 + 1] = l1 - lse;
}

extern "C" void kernel_launch(void* const* d_in, const int* in_sizes, int n_in,
                              void* d_out, int out_size, void* d_ws, size_t ws_size,
                              hipStream_t stream){
  const float* x    = (const float*)d_in[0];
  const int*   ei   = (const int*)d_in[1];
  const int*   batch= (const int*)d_in[2];
  const float* W0   = (const float*)d_in[3];
  const float* as0  = (const float*)d_in[4];
  const float* ad0  = (const float*)d_in[5];
  const float* b0   = (const float*)d_in[6];
  const float* W1   = (const float*)d_in[7];
  const float* as1  = (const float*)d_in[8];
  const float* ad1  = (const float*)d_in[9];
  const float* b1   = (const float*)d_in[10];
  const float* W2   = (const float*)d_in[11];
  const float* as2  = (const float*)d_in[12];
  const float* ad2  = (const float*)d_in[13];
  const float* b2   = (const float*)d_in[14];
  const float* bn0g = (const float*)d_in[15];
  const float* bn0b = (const float*)d_in[16];
  const float* bn1g = (const float*)d_in[17];
  const float* bn1b = (const float*)d_in[18];
  const float* bn2g = (const float*)d_in[19];
  const float* bn2b = (const float*)d_in[20];
  const float* lng  = (const float*)d_in[21];
  const float* lnb  = (const float*)d_in[22];
  const float* fc1w = (const float*)d_in[23];
  const float* fc1b = (const float*)d_in[24];
  const float* fc2w = (const float*)d_in[25];
  const float* fc2b = (const float*)d_in[26];
  float* out = (float*)d_out;

  char* w = (char*)d_ws;
  auto alloc = [&](size_t bytes) -> char* {
    char* p = w; w += (bytes + 255) & ~(size_t)255; return p;
  };
  __bf16* xb0   = (__bf16*)alloc((size_t)NODES*DIN*2);
  __bf16* hbuf  = (__bf16*)alloc((size_t)NODES*512*2);
  __bf16* gbuf  = (__bf16*)alloc((size_t)NODES*512*2);
  __bf16* x1b   = (__bf16*)alloc((size_t)NODES*512*2);
  __bf16* x2b   = (__bf16*)alloc((size_t)NODES*512*2);
  __bf16* Wt0   = (__bf16*)alloc((size_t)TW0*2);
  __bf16* Wt1   = (__bf16*)alloc((size_t)TW1*2);
  __bf16* Wt2   = (__bf16*)alloc((size_t)TW2*2);
  float*  ssrc  = (float*)alloc((size_t)NODES*8*4);
  float*  sdst  = (float*)alloc((size_t)NODES*8*4);
  float*  xl    = (float*)alloc((size_t)NODES*DH*4);
  float*  pooled= (float*)alloc(NGRAPH*DH*4);
  int*    rowptr= (int*)alloc((NODES+1)*4);
  int*    colA  = (int*)alloc((size_t)ETOT*4);
  float*  partial=(float*)alloc((size_t)2*512*512*4);
  float*  sum0  = (float*)alloc(512*4);
  float*  sq0   = (float*)alloc(512*4);
  float*  sum1  = (float*)alloc(512*4);
  float*  sq1   = (float*)alloc(512*4);
  float*  sum2  = (float*)alloc(64*4);
  float*  sq2   = (float*)alloc(64*4);
  char* zbase  = w;
  int*   deg   = (int*)alloc(NODES*4);
  int*   cursor= (int*)alloc(NODES*4);
  size_t zbytes = (size_t)(w - zbase);
  hipMemsetAsync(zbase, 0, zbytes, stream);

  const int eb = (ETOT + 255)/256;
  k_count<<<eb, 256, 0, stream>>>(ei, deg);
  k_scan<<<1, 1024, 0, stream>>>(deg, rowptr);
  k_fill<<<eb, 256, 0, stream>>>(ei, rowptr, cursor, colA);

  const int prep_total = NCAST4 + TW0 + TW1 + TW2;
  k_prep<<<(prep_total + 255)/256, 256, 0, stream>>>(x, xb0, W0, W1, W2, Wt0, Wt1, Wt2);

  const int mb128 = (NODES + 127)/128;
  const int nb8 = (NODES + 7)/8;

  // ---- layer 0: 256 -> 8x64 ----
  k_gemm_bf16<<<dim3(4, mb128), 256, 0, stream>>>(xb0, Wt0, hbuf, as0, ad0, ssrc, sdst, 8, NODES, 512, DIN);
  k_gatagg8<<<NODES, 256, 0, stream>>>(hbuf, ssrc, sdst, rowptr, colA, b0, gbuf);
  k_bnstat1<<<512, 256, 0, stream>>>(gbuf, partial, 512);
  k_bnstat2<<<1024, 64, 0, stream>>>(partial, sum0, sq0, 512, 512);
  k_bnapply_b<<<nb8, 256, 0, stream>>>(gbuf, sum0, sq0, bn0g, bn0b, nullptr, x1b, 8);

  // ---- layer 1: 512 -> 8x64, residual ----
  k_gemm_bf16<<<dim3(4, mb128), 256, 0, stream>>>(x1b, Wt1, hbuf, as1, ad1, ssrc, sdst, 8, NODES, 512, 512);
  k_gatagg8<<<NODES, 256, 0, stream>>>(hbuf, ssrc, sdst, rowptr, colA, b1, gbuf);
  k_bnstat1<<<512, 256, 0, stream>>>(gbuf, partial, 512);
  k_bnstat2<<<1024, 64, 0, stream>>>(partial, sum1, sq1, 512, 512);
  k_bnapply_b<<<nb8, 256, 0, stream>>>(gbuf, sum1, sq1, bn1g, bn1b, x1b, x2b, 8);

  // ---- layer 2: 512 -> 1x64 ----
  k_gemm_bf16<<<dim3(1, mb128), 256, 0, stream>>>(x2b, Wt2, hbuf, as2, ad2, ssrc, sdst, 1, NODES, 64, 512);
  k_gatagg1<<<NODES, 256, 0, stream>>>(hbuf, ssrc, sdst, rowptr, colA, b2, gbuf);
  k_bnstat1<<<256, 256, 0, stream>>>(gbuf, partial, 64);
  k_bnstat2<<<128, 64, 0, stream>>>(partial, sum2, sq2, 64, 256);
  k_bn_elu_ln_b<<<nb8, 256, 0, stream>>>(gbuf, sum2, sq2, bn2g, bn2b, lng, lnb, xl);

  k_pool<<<NGRAPH, 256, 0, stream>>>(xl, batch, pooled);
  k_head<<<1, 32, 0, stream>>>(pooled, fc1w, fc1b, fc2w, fc2b, out);
}